// Round 6
// baseline (330.264 us; speedup 1.0000x reference)
//
#include <hip/hip_runtime.h>
#include <math.h>

// B=8, C=64, H=512, W=512, K=8, HID=64, nh=nw=64, L=4096
//
//  A) mlp_precompute: pk[L][64], pb[L] into d_ws (runs once, ~8 us).
//  B) afpm_main: 8192 blocks x 512 threads = (c:64, pw:4, q:2); thread owns
//     half a patch (8 rows x 4 cols) = 8 float4 = 32 VGPR. ONE barrier.
//     R6 change vs R5: minimize VGPR to fit 8 waves/SIMD (4 blocks/CU,
//     32 waves — max occupancy):
//       - pk read in-loop from global (L2-resident 1 MiB) instead of kv[8] regs
//       - conv_w read directly from global in the conv loop (16 KB, L1-hot)
//         -> no convT LDS staging at all; LDS = f0T (1.1 KB) only
//     __launch_bounds__(512, 8) caps VGPR at 64.

static __device__ __forceinline__ float gelu_erf(float x) {
    return 0.5f * x * (1.0f + erff(x * 0.70710678118654752f));
}

__global__ __launch_bounds__(256) void mlp_precompute(
    const float* __restrict__ w1k, const float* __restrict__ b1k,
    const float* __restrict__ w2k, const float* __restrict__ b2k,
    const float* __restrict__ w1b, const float* __restrict__ b1b,
    const float* __restrict__ w2b, const float* __restrict__ b2b,
    float* __restrict__ pk_out,   // [L][64]
    float* __restrict__ pb_out)   // [L]
{
    constexpr int HID = 64;
    const int tid = threadIdx.x;
    const int pi  = tid >> 6;
    const int j   = tid & 63;
    const int l   = blockIdx.x * 4 + pi;

    const int py_i = l >> 6;
    const int px_i = l & 63;
    const float py = (float)(py_i * 8) + 4.0f - 256.0f;
    const float px = (float)(px_i * 8) + 4.0f - 256.0f;
    const float dd = sqrtf(py * py + px * px) * (1.0f / 362.03867196751236f);

    __shared__ float gk[4][HID];
    __shared__ float gb[4][HID];

    gk[pi][j] = gelu_erf(dd * w1k[j] + b1k[j]);
    gb[pi][j] = gelu_erf(dd * w1b[j] + b1b[j]);
    __syncthreads();

    float s = b2k[j];
#pragma unroll 8
    for (int h = 0; h < HID; ++h)
        s += gk[pi][h] * w2k[h * HID + j];
    pk_out[l * HID + j] = s;

    if (j == 0) {
        float t = b2b[0];
        for (int h = 0; h < HID; ++h)
            t += gb[pi][h] * w2b[h];
        pb_out[l] = t;
    }
}

__global__ __launch_bounds__(512, 8) void afpm_main(
    const float* __restrict__ x,
    const float* __restrict__ conv_w, const float* __restrict__ conv_b,
    const float* __restrict__ pk_g,   // [L][64]
    const float* __restrict__ pb_g,   // [L]
    float* __restrict__ out)
{
    constexpr int W = 512;

    const int tid = threadIdx.x;
    const int q   = tid & 1;          // column half (cols q*4..q*4+3)
    const int pw  = (tid >> 1) & 3;   // patch within group
    const int c   = tid >> 3;         // channel
    const int pwg = blockIdx.x;       // 0..15
    const int ph  = blockIdx.y;       // 0..63
    const int b   = blockIdx.z;       // 0..7

    __shared__ float f0T[4][68];      // [pw][cc], pad 68

    const int l = ph * 64 + pwg * 4 + pw;   // global patch index

    // ---- pixel loads (8 float4 = 8 fully-utilized 128B lines per instr) ----
    const size_t cbase = (((size_t)b * 64 + c) * 512 + (size_t)ph * 8) * (size_t)W
                         + (size_t)(pwg * 32 + pw * 8 + q * 4);
    const float* xp = x + cbase;
    float4 v[8];
#pragma unroll
    for (int r = 0; r < 8; ++r)
        v[r] = *(const float4*)(xp + r * W);

    // ---- dot(patch-half, pk-half); pk read in-loop (L2-resident table) ----
    const float4* pkp = (const float4*)pk_g + (size_t)l * 16 + q;
    float s = 0.0f;
#pragma unroll
    for (int r = 0; r < 8; ++r) {
        const float4 kv = pkp[r * 2];
        s += v[r].x * kv.x + v[r].y * kv.y + v[r].z * kv.z + v[r].w * kv.w;
    }
    s += __shfl_xor(s, 1);            // combine column halves
    if (q == 0)
        f0T[pw][c] = s + pb_g[l];     // pb folded here

    __syncthreads();                  // the ONE barrier

    // ---- per-thread 1x1 conv, q-split; conv_w direct from global (L1-hot) --
    const float4* cw  = (const float4*)(conv_w + (size_t)c * 64 + q * 32);
    const float*  f0p = &f0T[pw][q * 32];
    float t = 0.0f;
#pragma unroll
    for (int i4 = 0; i4 < 8; ++i4) {
        const float4 w = cw[i4];
        const float4 f = *(const float4*)(f0p + i4 * 4);
        t += w.x * f.x + w.y * f.y + w.z * f.z + w.w * f.w;
    }
    t += __shfl_xor(t, 1);            // combine the two cc-halves
    const float m = t + conv_b[c];

    // ---- modulate + store ----
    float* op = out + cbase;
#pragma unroll
    for (int r = 0; r < 8; ++r) {
        float4 a = v[r];
        a.x *= m; a.y *= m; a.z *= m; a.w *= m;
        *(float4*)(op + r * W) = a;
    }
}

extern "C" void kernel_launch(void* const* d_in, const int* in_sizes, int n_in,
                              void* d_out, int out_size, void* d_ws, size_t ws_size,
                              hipStream_t stream) {
    const float* x      = (const float*)d_in[0];
    const float* w1k    = (const float*)d_in[1];
    const float* b1k    = (const float*)d_in[2];
    const float* w2k    = (const float*)d_in[3];
    const float* b2k    = (const float*)d_in[4];
    const float* w1b    = (const float*)d_in[5];
    const float* b1b    = (const float*)d_in[6];
    const float* w2b    = (const float*)d_in[7];
    const float* b2b    = (const float*)d_in[8];
    const float* conv_w = (const float*)d_in[9];
    const float* conv_b = (const float*)d_in[10];
    float* out = (float*)d_out;

    constexpr int L = 64 * 64;
    float* pk = (float*)d_ws;            // L*64 floats = 1 MiB
    float* pb = pk + (size_t)L * 64;     // L floats

    mlp_precompute<<<L / 4, 256, 0, stream>>>(w1k, b1k, w2k, b2k,
                                              w1b, b1b, w2b, b2b, pk, pb);

    dim3 grid(16, 64, 8);
    afpm_main<<<grid, 512, 0, stream>>>(x, conv_w, conv_b, pk, pb, out);
}

// Round 7
// 233.960 us; speedup vs baseline: 1.4116x; 1.4116x over previous
//
#include <hip/hip_runtime.h>
#include <math.h>

// B=8, C=64, H=512, W=512, K=8, HID=64, nh=nw=64, L=4096
//
//  A) mlp_precompute: pk[L][64], pb[L] into d_ws (runs once, ~8 us).
//  B) afpm_main (R7): kill the 1.62x HBM write amplification seen in R6
//     (832 MiB written vs 512 ideal; 128B chunks half-fill 256B granules,
//     the other half belonging to the neighboring pwg block).
//     Block tile = c64 x r8 x 64 contiguous cols (8 patches), 512 threads,
//     16 float4/thread. Per wave, the two store instrs per (c,r) cover the
//     full 256B granule from within the same wave -> no partial granules.
//     Thread (c,u): cols [4u..4u+3] of half0 (patch u>>1) and half1
//     (patch 4+(u>>1)). Dot halves combine via __shfl_xor(,1); conv: one
//     (c,p=u) output per thread; modulators fetched via in-wave __shfl.
//     pk/pb staged in LDS (1 float/thread). Two barriers.

static __device__ __forceinline__ float gelu_erf(float x) {
    return 0.5f * x * (1.0f + erff(x * 0.70710678118654752f));
}

__global__ __launch_bounds__(256) void mlp_precompute(
    const float* __restrict__ w1k, const float* __restrict__ b1k,
    const float* __restrict__ w2k, const float* __restrict__ b2k,
    const float* __restrict__ w1b, const float* __restrict__ b1b,
    const float* __restrict__ w2b, const float* __restrict__ b2b,
    float* __restrict__ pk_out,   // [L][64]
    float* __restrict__ pb_out)   // [L]
{
    constexpr int HID = 64;
    const int tid = threadIdx.x;
    const int pi  = tid >> 6;
    const int j   = tid & 63;
    const int l   = blockIdx.x * 4 + pi;

    const int py_i = l >> 6;
    const int px_i = l & 63;
    const float py = (float)(py_i * 8) + 4.0f - 256.0f;
    const float px = (float)(px_i * 8) + 4.0f - 256.0f;
    const float dd = sqrtf(py * py + px * px) * (1.0f / 362.03867196751236f);

    __shared__ float gk[4][HID];
    __shared__ float gb[4][HID];

    gk[pi][j] = gelu_erf(dd * w1k[j] + b1k[j]);
    gb[pi][j] = gelu_erf(dd * w1b[j] + b1b[j]);
    __syncthreads();

    float s = b2k[j];
#pragma unroll 8
    for (int h = 0; h < HID; ++h)
        s += gk[pi][h] * w2k[h * HID + j];
    pk_out[l * HID + j] = s;

    if (j == 0) {
        float t = b2b[0];
        for (int h = 0; h < HID; ++h)
            t += gb[pi][h] * w2b[h];
        pb_out[l] = t;
    }
}

__global__ __launch_bounds__(512, 4) void afpm_main(
    const float* __restrict__ x,
    const float* __restrict__ conv_w, const float* __restrict__ conv_b,
    const float* __restrict__ pk_g,   // [L][64]
    const float* __restrict__ pb_g,   // [L]
    float* __restrict__ out)
{
    constexpr int W = 512;

    const int tid  = threadIdx.x;
    const int u    = tid & 7;          // 0..7: 4-col slice within each half
    const int c    = tid >> 3;         // 0..63 channel
    const int pwg2 = blockIdx.x;       // 0..7 : 64-col tile
    const int ph   = blockIdx.y;       // 0..63
    const int b    = blockIdx.z;       // 0..7

    __shared__ float pkL[8][68];       // 8 patches x 64 kernel elems (pad 68)
    __shared__ float f0T[8][68];       // [patch][cc], pad 68
    __shared__ float pbL[8];

    const int lbase = ph * 64 + pwg2 * 8;   // first global patch of tile

    // ---- pixel loads: 16 float4; per (c,r) the two instrs cover 256B ----
    const size_t base = (((size_t)b * 64 + c) * 512 + (size_t)ph * 8) * (size_t)W
                        + (size_t)(pwg2 * 64);
    const float* xp0 = x + base + 4 * u;        // half0: cols [4u..4u+3]
    const float* xp1 = x + base + 32 + 4 * u;   // half1: +32
    float4 v0[8], v1[8];
#pragma unroll
    for (int r = 0; r < 8; ++r) {
        v0[r] = *(const float4*)(xp0 + r * W);
        v1[r] = *(const float4*)(xp1 + r * W);
    }

    // ---- stage pk (512 floats = 1/thread) and pb ----
    pkL[tid >> 6][tid & 63] = pk_g[(size_t)lbase * 64 + tid];
    if (tid < 8) pbL[tid] = pb_g[lbase + tid];
    __syncthreads();                       // barrier 1

    // ---- per-thread partial dots for the two patches ----
    const int p0 = u >> 1;                 // patch in half0 (0..3)
    const int p1 = 4 + (u >> 1);           // patch in half1 (4..7)
    const int co = (u & 1) * 4;            // col offset within patch
    float s0 = 0.0f, s1 = 0.0f;
#pragma unroll
    for (int r = 0; r < 8; ++r) {
        const int k0 = r * 8 + co;
        const float4 a = v0[r];
        s0 += a.x * pkL[p0][k0 + 0] + a.y * pkL[p0][k0 + 1]
            + a.z * pkL[p0][k0 + 2] + a.w * pkL[p0][k0 + 3];
        const float4 d = v1[r];
        s1 += d.x * pkL[p1][k0 + 0] + d.y * pkL[p1][k0 + 1]
            + d.z * pkL[p1][k0 + 2] + d.w * pkL[p1][k0 + 3];
    }
    s0 += __shfl_xor(s0, 1);               // combine 4-col halves of patch
    s1 += __shfl_xor(s1, 1);
    if ((u & 1) == 0) f0T[p0][c] = s0 + pbL[p0];
    else              f0T[p1][c] = s1 + pbL[p1];
    __syncthreads();                       // barrier 2

    // ---- conv: thread (c,u) computes modulator for (o=c, patch=u) ----
    float t = 0.0f;
    const float4* cw = (const float4*)(conv_w + (size_t)c * 64);
#pragma unroll
    for (int i = 0; i < 16; ++i) {
        const float4 w = cw[i];
        const float4 f = *(const float4*)&f0T[u][i * 4];
        t += w.x * f.x + w.y * f.y + w.z * f.z + w.w * f.w;
    }
    const float m_self = t + conv_b[c];

    // fetch this thread's two modulators from the in-wave c-group
    const int lane  = tid & 63;
    const int laneC = lane - u;            // first lane of this c-group
    const float m0 = __shfl(m_self, laneC + p0);
    const float m1 = __shfl(m_self, laneC + p1);

    // ---- modulate + store (same granule-complete pattern as loads) ----
    float* op0 = out + base + 4 * u;
    float* op1 = out + base + 32 + 4 * u;
#pragma unroll
    for (int r = 0; r < 8; ++r) {
        float4 a = v0[r];
        a.x *= m0; a.y *= m0; a.z *= m0; a.w *= m0;
        *(float4*)(op0 + r * W) = a;
        float4 d = v1[r];
        d.x *= m1; d.y *= m1; d.z *= m1; d.w *= m1;
        *(float4*)(op1 + r * W) = d;
    }
}

extern "C" void kernel_launch(void* const* d_in, const int* in_sizes, int n_in,
                              void* d_out, int out_size, void* d_ws, size_t ws_size,
                              hipStream_t stream) {
    const float* x      = (const float*)d_in[0];
    const float* w1k    = (const float*)d_in[1];
    const float* b1k    = (const float*)d_in[2];
    const float* w2k    = (const float*)d_in[3];
    const float* b2k    = (const float*)d_in[4];
    const float* w1b    = (const float*)d_in[5];
    const float* b1b    = (const float*)d_in[6];
    const float* w2b    = (const float*)d_in[7];
    const float* b2b    = (const float*)d_in[8];
    const float* conv_w = (const float*)d_in[9];
    const float* conv_b = (const float*)d_in[10];
    float* out = (float*)d_out;

    constexpr int L = 64 * 64;
    float* pk = (float*)d_ws;            // L*64 floats = 1 MiB
    float* pb = pk + (size_t)L * 64;     // L floats

    mlp_precompute<<<L / 4, 256, 0, stream>>>(w1k, b1k, w2k, b2k,
                                              w1b, b1b, w2b, b2b, pk, pb);

    // 4096 blocks: (64-col tile: 8) x (ph: 64) x (b: 8)
    dim3 grid(8, 64, 8);
    afpm_main<<<grid, 512, 0, stream>>>(x, conv_w, conv_b, pk, pb, out);
}

// Round 8
// 226.366 us; speedup vs baseline: 1.4590x; 1.0335x over previous
//
#include <hip/hip_runtime.h>
#include <math.h>

// B=8, C=64, H=512, W=512, K=8, HID=64, nh=nw=64, L=4096
//
//  A) mlp_precompute: pk[L][64], pb[L] into d_ws (runs once, ~8 us).
//  B) afpm_main (R8): widen per-instruction contiguous span per channel-plane.
//     1024 threads = (c:64 x u:16); tile = 64c x 8r x 128 cols (16 patches).
//     Per wave-instruction: 4 planes x 256 B (vs R7's 8 x 128 B); per
//     instruction pair 512 B/plane; each 2 KB image row owned by 4 blocks
//     (vs 8). Two barriers; pk/pb staged in LDS; per-thread conv; modulators
//     exchanged via in-wave __shfl within the 16-lane c-group.

static __device__ __forceinline__ float gelu_erf(float x) {
    return 0.5f * x * (1.0f + erff(x * 0.70710678118654752f));
}

__global__ __launch_bounds__(256) void mlp_precompute(
    const float* __restrict__ w1k, const float* __restrict__ b1k,
    const float* __restrict__ w2k, const float* __restrict__ b2k,
    const float* __restrict__ w1b, const float* __restrict__ b1b,
    const float* __restrict__ w2b, const float* __restrict__ b2b,
    float* __restrict__ pk_out,   // [L][64]
    float* __restrict__ pb_out)   // [L]
{
    constexpr int HID = 64;
    const int tid = threadIdx.x;
    const int pi  = tid >> 6;
    const int j   = tid & 63;
    const int l   = blockIdx.x * 4 + pi;

    const int py_i = l >> 6;
    const int px_i = l & 63;
    const float py = (float)(py_i * 8) + 4.0f - 256.0f;
    const float px = (float)(px_i * 8) + 4.0f - 256.0f;
    const float dd = sqrtf(py * py + px * px) * (1.0f / 362.03867196751236f);

    __shared__ float gk[4][HID];
    __shared__ float gb[4][HID];

    gk[pi][j] = gelu_erf(dd * w1k[j] + b1k[j]);
    gb[pi][j] = gelu_erf(dd * w1b[j] + b1b[j]);
    __syncthreads();

    float s = b2k[j];
#pragma unroll 8
    for (int h = 0; h < HID; ++h)
        s += gk[pi][h] * w2k[h * HID + j];
    pk_out[l * HID + j] = s;

    if (j == 0) {
        float t = b2b[0];
        for (int h = 0; h < HID; ++h)
            t += gb[pi][h] * w2b[h];
        pb_out[l] = t;
    }
}

__global__ __launch_bounds__(1024, 4) void afpm_main(
    const float* __restrict__ x,
    const float* __restrict__ conv_w, const float* __restrict__ conv_b,
    const float* __restrict__ pk_g,   // [L][64]
    const float* __restrict__ pb_g,   // [L]
    float* __restrict__ out)
{
    constexpr int W = 512;

    const int tid  = threadIdx.x;
    const int u    = tid & 15;         // 0..15: 4-col slice within each half
    const int c    = tid >> 4;         // 0..63 channel
    const int tile = blockIdx.x;       // 0..3 : 128-col tile
    const int ph   = blockIdx.y;       // 0..63
    const int b    = blockIdx.z;       // 0..7

    __shared__ float pkL[16][68];      // 16 patches x 64 kernel elems (pad 68)
    __shared__ float f0T[16][68];      // [patch][cc], pad 68
    __shared__ float pbL[16];

    const int lbase = ph * 64 + tile * 16;   // first global patch of tile

    // ---- pixel loads: 16 float4; wave covers 4 planes x 512B per instr-pair
    const size_t base = (((size_t)b * 64 + c) * 512 + (size_t)ph * 8) * (size_t)W
                        + (size_t)(tile * 128);
    const float* xp0 = x + base + 4 * u;        // half0: cols [4u..4u+3]
    const float* xp1 = x + base + 64 + 4 * u;   // half1: +64
    float4 v0[8], v1[8];
#pragma unroll
    for (int r = 0; r < 8; ++r) {
        v0[r] = *(const float4*)(xp0 + r * W);
        v1[r] = *(const float4*)(xp1 + r * W);
    }

    // ---- stage pk (1024 floats = 1/thread) and pb ----
    pkL[tid >> 6][tid & 63] = pk_g[(size_t)lbase * 64 + tid];
    if (tid < 16) pbL[tid] = pb_g[lbase + tid];
    __syncthreads();                       // barrier 1

    // ---- per-thread partial dots for the two patches ----
    const int p0 = u >> 1;                 // patch in half0 (0..7)
    const int p1 = 8 + (u >> 1);           // patch in half1 (8..15)
    const int co = (u & 1) * 4;            // col offset within patch
    float s0 = 0.0f, s1 = 0.0f;
#pragma unroll
    for (int r = 0; r < 8; ++r) {
        const int k0 = r * 8 + co;
        const float4 a = v0[r];
        s0 += a.x * pkL[p0][k0 + 0] + a.y * pkL[p0][k0 + 1]
            + a.z * pkL[p0][k0 + 2] + a.w * pkL[p0][k0 + 3];
        const float4 d = v1[r];
        s1 += d.x * pkL[p1][k0 + 0] + d.y * pkL[p1][k0 + 1]
            + d.z * pkL[p1][k0 + 2] + d.w * pkL[p1][k0 + 3];
    }
    s0 += __shfl_xor(s0, 1);               // combine 4-col halves of patch
    s1 += __shfl_xor(s1, 1);
    if ((u & 1) == 0) f0T[p0][c] = s0 + pbL[p0];
    else              f0T[p1][c] = s1 + pbL[p1];
    __syncthreads();                       // barrier 2

    // ---- conv: thread (c,u) computes modulator for (o=c, patch=u) ----
    float t = 0.0f;
    const float4* cw = (const float4*)(conv_w + (size_t)c * 64);
#pragma unroll
    for (int i = 0; i < 16; ++i) {
        const float4 w = cw[i];
        const float4 f = *(const float4*)&f0T[u][i * 4];
        t += w.x * f.x + w.y * f.y + w.z * f.z + w.w * f.w;
    }
    const float m_self = t + conv_b[c];

    // fetch this thread's two modulators from the in-wave 16-lane c-group
    const int lane  = tid & 63;
    const int laneC = lane & 48;           // first lane of this c-group
    const float m0 = __shfl(m_self, laneC + p0);
    const float m1 = __shfl(m_self, laneC + p1);

    // ---- modulate + store (same span pattern as loads) ----
    float* op0 = out + base + 4 * u;
    float* op1 = out + base + 64 + 4 * u;
#pragma unroll
    for (int r = 0; r < 8; ++r) {
        float4 a = v0[r];
        a.x *= m0; a.y *= m0; a.z *= m0; a.w *= m0;
        *(float4*)(op0 + r * W) = a;
        float4 d = v1[r];
        d.x *= m1; d.y *= m1; d.z *= m1; d.w *= m1;
        *(float4*)(op1 + r * W) = d;
    }
}

extern "C" void kernel_launch(void* const* d_in, const int* in_sizes, int n_in,
                              void* d_out, int out_size, void* d_ws, size_t ws_size,
                              hipStream_t stream) {
    const float* x      = (const float*)d_in[0];
    const float* w1k    = (const float*)d_in[1];
    const float* b1k    = (const float*)d_in[2];
    const float* w2k    = (const float*)d_in[3];
    const float* b2k    = (const float*)d_in[4];
    const float* w1b    = (const float*)d_in[5];
    const float* b1b    = (const float*)d_in[6];
    const float* w2b    = (const float*)d_in[7];
    const float* b2b    = (const float*)d_in[8];
    const float* conv_w = (const float*)d_in[9];
    const float* conv_b = (const float*)d_in[10];
    float* out = (float*)d_out;

    constexpr int L = 64 * 64;
    float* pk = (float*)d_ws;            // L*64 floats = 1 MiB
    float* pb = pk + (size_t)L * 64;     // L floats

    mlp_precompute<<<L / 4, 256, 0, stream>>>(w1k, b1k, w2k, b2k,
                                              w1b, b1b, w2b, b2b, pk, pb);

    // 2048 blocks: (128-col tile: 4) x (ph: 64) x (b: 8)
    dim3 grid(4, 64, 8);
    afpm_main<<<grid, 1024, 0, stream>>>(x, conv_w, conv_b, pk, pb, out);
}